// Round 1
// baseline (1473.168 us; speedup 1.0000x reference)
//
#include <hip/hip_runtime.h>
#include <math.h>

#define NENT 50000
#define NREL 500
#define DIM 256
#define BATCH 512
#define EPSV 1e-5f

// ws layout (in floats)
#define WS_ACC    0                       // 4096: accE_sum(1024), accE_sq(1024), accH_sum(1024), accH_sq(1024)
#define WS_STATS  4096                    // 4096: meanE(1024), invstdE(1024), meanH(1024), invstdH(1024)
#define WS_TP     8192                    // 4*512*256 = 524288
#define WS_KC     (8192 + 4*BATCH*DIM)    // 4*512 = 2048

// ---------------- Phase 1: BN stats over ALL entities (qnorm'd) ----------------
__global__ void stats_all_kernel(const float* __restrict__ E, float* __restrict__ acc) {
    int d = threadIdx.x;  // 256
    int per = (NENT + gridDim.x - 1) / gridDim.x;
    int n0 = blockIdx.x * per;
    int n1 = n0 + per; if (n1 > NENT) n1 = NENT;
    float sm0=0,sm1=0,sm2=0,sm3=0, sq0=0,sq1=0,sq2=0,sq3=0;
    for (int n = n0; n < n1; ++n) {
        int ga = n*DIM + d;
        float e0 = E[ga];
        float e1 = E[1*NENT*DIM + ga];
        float e2 = E[2*NENT*DIM + ga];
        float e3 = E[3*NENT*DIM + ga];
        float inv = rsqrtf(e0*e0+e1*e1+e2*e2+e3*e3);
        e0*=inv; e1*=inv; e2*=inv; e3*=inv;
        sm0+=e0; sq0+=e0*e0;
        sm1+=e1; sq1+=e1*e1;
        sm2+=e2; sq2+=e2*e2;
        sm3+=e3; sq3+=e3*e3;
    }
    atomicAdd(&acc[0*DIM+d], sm0); atomicAdd(&acc[1024 + 0*DIM+d], sq0);
    atomicAdd(&acc[1*DIM+d], sm1); atomicAdd(&acc[1024 + 1*DIM+d], sq1);
    atomicAdd(&acc[2*DIM+d], sm2); atomicAdd(&acc[1024 + 2*DIM+d], sq2);
    atomicAdd(&acc[3*DIM+d], sm3); atomicAdd(&acc[1024 + 3*DIM+d], sq3);
}

// ---------------- Phase 2: BN stats over gathered batch h ----------------
__global__ void stats_batch_kernel(const float* __restrict__ E, const int* __restrict__ h_idx,
                                   float* __restrict__ accH) {
    int d = threadIdx.x;
    int b0 = blockIdx.x * 32;  // 16 blocks x 32 rows = 512
    float sm0=0,sm1=0,sm2=0,sm3=0, sq0=0,sq1=0,sq2=0,sq3=0;
    for (int j = 0; j < 32; ++j) {
        int n = h_idx[b0 + j];
        int ga = n*DIM + d;
        float e0 = E[ga];
        float e1 = E[1*NENT*DIM + ga];
        float e2 = E[2*NENT*DIM + ga];
        float e3 = E[3*NENT*DIM + ga];
        float inv = rsqrtf(e0*e0+e1*e1+e2*e2+e3*e3);
        e0*=inv; e1*=inv; e2*=inv; e3*=inv;
        sm0+=e0; sq0+=e0*e0;
        sm1+=e1; sq1+=e1*e1;
        sm2+=e2; sq2+=e2*e2;
        sm3+=e3; sq3+=e3*e3;
    }
    atomicAdd(&accH[0*DIM+d], sm0); atomicAdd(&accH[1024 + 0*DIM+d], sq0);
    atomicAdd(&accH[1*DIM+d], sm1); atomicAdd(&accH[1024 + 1*DIM+d], sq1);
    atomicAdd(&accH[2*DIM+d], sm2); atomicAdd(&accH[1024 + 2*DIM+d], sq2);
    atomicAdd(&accH[3*DIM+d], sm3); atomicAdd(&accH[1024 + 3*DIM+d], sq3);
}

// ---------------- Phase 3: finalize stats ----------------
__global__ void finalize_stats_kernel(const float* __restrict__ acc, float* __restrict__ stats) {
    int i = blockIdx.x * blockDim.x + threadIdx.x;  // 0..1023 -> (c,d)
    float mE = acc[i] * (1.0f / NENT);
    float vE = acc[1024 + i] * (1.0f / NENT) - mE * mE;
    float mH = acc[2048 + i] * (1.0f / BATCH);
    float vH = acc[3072 + i] * (1.0f / BATCH) - mH * mH;
    stats[i]        = mE;
    stats[1024 + i] = rsqrtf(vE + EPSV);
    stats[2048 + i] = mH;
    stats[3072 + i] = rsqrtf(vH + EPSV);
}

// ---------------- Phase 4: build t' (BN-folded) and K[c][b] ----------------
__global__ void build_t_kernel(const float* __restrict__ E, const float* __restrict__ R,
                               const float* __restrict__ psi_emb,
                               const float* __restrict__ gamma, const float* __restrict__ beta,
                               const int* __restrict__ h_idx, const int* __restrict__ r_idx,
                               const float* __restrict__ stats,
                               float* __restrict__ tp, float* __restrict__ Kc) {
    __shared__ float red[256];
    int b = blockIdx.x, d = threadIdx.x;
    int hn = h_idx[b], rn = r_idx[b];

    float hv[4];
    hv[0] = E[hn*DIM + d];
    hv[1] = E[1*NENT*DIM + hn*DIM + d];
    hv[2] = E[2*NENT*DIM + hn*DIM + d];
    hv[3] = E[3*NENT*DIM + hn*DIM + d];
    float invh = rsqrtf(hv[0]*hv[0]+hv[1]*hv[1]+hv[2]*hv[2]+hv[3]*hv[3]);
    float hq[4];
#pragma unroll
    for (int c = 0; c < 4; ++c) {
        float v = hv[c] * invh;
        float mH = stats[2048 + c*DIM + d], isH = stats[3072 + c*DIM + d];
        hq[c] = (v - mH) * isH * gamma[c*DIM + d] + beta[c*DIM + d];
    }

    float r0 = R[rn*DIM + d];
    float r1 = R[1*NREL*DIM + rn*DIM + d];
    float r2 = R[2*NREL*DIM + rn*DIM + d];
    float r3 = R[3*NREL*DIM + rn*DIM + d];
    float invr = rsqrtf(r0*r0+r1*r1+r2*r2+r3*r3);
    r0*=invr; r1*=invr; r2*=invr; r3*=invr;

    float p = psi_emb[rn*DIM + d];
    float cz = cosf(p), sz = sinf(p);

    float m1r = hq[0]*r0 - hq[1]*r1;
    float m1i = hq[0]*r1 + hq[1]*r0;
    float X   = hq[2]*r2 + hq[3]*r3;   // h_b * conj(r_b) (re)
    float Y   = hq[3]*r2 - hq[2]*r3;   // (im)
    float m2r = cz*X - sz*Y;
    float m2i = cz*Y + sz*X;
    float m3r = hq[0]*r2 - hq[1]*r3;
    float m3i = hq[0]*r3 + hq[1]*r2;
    float U   = hq[2]*r0 + hq[3]*r1;   // h_b * conj(r_a) (re)
    float V   = hq[3]*r0 - hq[2]*r1;   // (im)
    float m4r = cz*U - sz*V;
    float m4i = cz*V + sz*U;

    float t[4] = { m1r - m2r, m1i - m2i, m3r + m4r, m3i + m4i };

#pragma unroll
    for (int c = 0; c < 4; ++c) {
        float g   = gamma[c*DIM + d];
        float mE  = stats[c*DIM + d];
        float isE = stats[1024 + c*DIM + d];
        tp[(c*BATCH + b)*DIM + d] = t[c] * g * isE;
        float kpart = t[c] * (beta[c*DIM + d] - g * mE * isE);
        red[d] = kpart;
        __syncthreads();
        for (int s = 128; s > 0; s >>= 1) {
            if (d < s) red[d] += red[d + s];
            __syncthreads();
        }
        if (d == 0) Kc[c*BATCH + b] = red[0];
        __syncthreads();
    }
}

// ---------------- Phase 5: GEMM + bias + sigmoid ----------------
// Tile: 64 n x 64 b x 4 c per 256-thread block; K-chunk 16.
#define NT 64
#define BT 64
#define KT 16
#define PAD 68

__launch_bounds__(256)
__global__ void score_gemm_kernel(const float* __restrict__ E,    // [4][NENT][DIM]
                                  const float* __restrict__ tp,   // [4][BATCH][DIM]
                                  const float* __restrict__ Kc,   // [4][BATCH]
                                  const float* __restrict__ biases, // [4][NENT]
                                  float* __restrict__ out) {      // [4][BATCH][NENT]
    __shared__ float sE[4][KT][PAD];  // [c][dd][n]
    __shared__ float sT[4][KT][PAD];  // [c][dd][b]
    int tid = threadIdx.x;
    int n0 = blockIdx.x * NT;
    int b0 = blockIdx.y * BT;
    int ng = (tid & 15) * 4;   // this thread's 4 n (contig)
    int bg = (tid >> 4) * 4;   // this thread's 4 b (contig)

    float acc[4][4][4];  // [c][b][n]
#pragma unroll
    for (int c = 0; c < 4; ++c)
#pragma unroll
        for (int i = 0; i < 4; ++i)
#pragma unroll
            for (int j = 0; j < 4; ++j) acc[c][i][j] = 0.f;

    for (int k0 = 0; k0 < DIM; k0 += KT) {
        __syncthreads();
        // stage E tile: qnorm on the fly. 4c*16dd*64n = 4096 (c-fused) -> 1024 (n,dd) pairs
#pragma unroll
        for (int i = 0; i < 4; ++i) {
            int p = tid + i * 256;
            int dd = p & (KT - 1);
            int nn = p >> 4;
            int n = n0 + nn; if (n > NENT - 1) n = NENT - 1;
            int ga = n*DIM + k0 + dd;
            float e0 = E[ga];
            float e1 = E[1*NENT*DIM + ga];
            float e2 = E[2*NENT*DIM + ga];
            float e3 = E[3*NENT*DIM + ga];
            float inv = rsqrtf(e0*e0+e1*e1+e2*e2+e3*e3);
            sE[0][dd][nn] = e0*inv;
            sE[1][dd][nn] = e1*inv;
            sE[2][dd][nn] = e2*inv;
            sE[3][dd][nn] = e3*inv;
        }
        // stage t' tile
#pragma unroll
        for (int i = 0; i < 4; ++i) {
            int p = tid + i * 256;
            int dd = p & (KT - 1);
            int bb = p >> 4;
            int b = b0 + bb;
            int ga = b*DIM + k0 + dd;
            sT[0][dd][bb] = tp[ga];
            sT[1][dd][bb] = tp[1*BATCH*DIM + ga];
            sT[2][dd][bb] = tp[2*BATCH*DIM + ga];
            sT[3][dd][bb] = tp[3*BATCH*DIM + ga];
        }
        __syncthreads();

#pragma unroll 4
        for (int dd = 0; dd < KT; ++dd) {
            float4 ef[4], tf[4];
#pragma unroll
            for (int c = 0; c < 4; ++c) {
                ef[c] = *(const float4*)&sE[c][dd][ng];
                tf[c] = *(const float4*)&sT[c][dd][bg];
            }
#pragma unroll
            for (int c = 0; c < 4; ++c) {
                const float tb[4] = { tf[c].x, tf[c].y, tf[c].z, tf[c].w };
                const float en[4] = { ef[c].x, ef[c].y, ef[c].z, ef[c].w };
#pragma unroll
                for (int i = 0; i < 4; ++i)
#pragma unroll
                    for (int j = 0; j < 4; ++j)
                        acc[c][i][j] = fmaf(tb[i], en[j], acc[c][i][j]);
            }
        }
    }

    // epilogue: + K[c][b] + bias[c][n], sigmoid, float4 store
    int n = n0 + ng;
    if (n < NENT) {
#pragma unroll
        for (int c = 0; c < 4; ++c) {
            const float4 b4 = *(const float4*)&biases[c*NENT + n];
            const float bias[4] = { b4.x, b4.y, b4.z, b4.w };
#pragma unroll
            for (int i = 0; i < 4; ++i) {
                int b = b0 + bg + i;
                float kb = Kc[c*BATCH + b];
                float4 o;
                o.x = 1.f / (1.f + expf(-(acc[c][i][0] + kb + bias[0])));
                o.y = 1.f / (1.f + expf(-(acc[c][i][1] + kb + bias[1])));
                o.z = 1.f / (1.f + expf(-(acc[c][i][2] + kb + bias[2])));
                o.w = 1.f / (1.f + expf(-(acc[c][i][3] + kb + bias[3])));
                *(float4*)&out[((size_t)(c*BATCH + b))*NENT + n] = o;
            }
        }
    }
}

extern "C" void kernel_launch(void* const* d_in, const int* in_sizes, int n_in,
                              void* d_out, int out_size, void* d_ws, size_t ws_size,
                              hipStream_t stream) {
    const float* E      = (const float*)d_in[0];
    const float* R      = (const float*)d_in[1];
    const float* psi    = (const float*)d_in[2];
    const float* gamma  = (const float*)d_in[3];
    const float* beta   = (const float*)d_in[4];
    const float* biases = (const float*)d_in[5];
    const int* h_idx    = (const int*)d_in[6];
    const int* r_idx    = (const int*)d_in[7];
    float* out = (float*)d_out;
    float* ws  = (float*)d_ws;

    // zero the atomic accumulator region (ws is poisoned before every call)
    hipMemsetAsync(ws + WS_ACC, 0, 4096 * sizeof(float), stream);

    stats_all_kernel<<<512, 256, 0, stream>>>(E, ws + WS_ACC);
    stats_batch_kernel<<<16, 256, 0, stream>>>(E, h_idx, ws + WS_ACC + 2048);
    finalize_stats_kernel<<<4, 256, 0, stream>>>(ws + WS_ACC, ws + WS_STATS);
    build_t_kernel<<<BATCH, 256, 0, stream>>>(E, R, psi, gamma, beta, h_idx, r_idx,
                                              ws + WS_STATS, ws + WS_TP, ws + WS_KC);
    dim3 grid((NENT + NT - 1) / NT, BATCH / BT);
    score_gemm_kernel<<<grid, 256, 0, stream>>>(E, ws + WS_TP, ws + WS_KC, biases, out);
}

// Round 2
// 742.420 us; speedup vs baseline: 1.9843x; 1.9843x over previous
//
#include <hip/hip_runtime.h>
#include <math.h>

#define NENT 50000
#define NREL 500
#define DIM 256
#define BATCH 512
#define EPSV 1e-5f

// ws layout: floats [0,10240) = acc(4096) stats(4096) Kc(2048); then f16 tables
#define WS_ACC    0
#define WS_STATS  4096
#define WS_KC     8192
#define WS_F16    10240   // th: 4*512*256 halves, then Eh: 4*50000*256 halves

typedef _Float16 f16x8 __attribute__((ext_vector_type(8)));
typedef float f32x16 __attribute__((ext_vector_type(16)));

__device__ inline f32x16 zero16() {
    f32x16 v;
#pragma unroll
    for (int i = 0; i < 16; ++i) v[i] = 0.f;
    return v;
}

// ---------------- Phase 1: qnorm + f16 convert + BN stats over ALL entities ----------------
__global__ void convert_stats_kernel(const float* __restrict__ E, _Float16* __restrict__ Eh,
                                     float* __restrict__ acc) {
    int d = threadIdx.x;  // 256
    int per = (NENT + gridDim.x - 1) / gridDim.x;
    int n0 = blockIdx.x * per;
    int n1 = n0 + per; if (n1 > NENT) n1 = NENT;
    float sm0=0,sm1=0,sm2=0,sm3=0, sq0=0,sq1=0,sq2=0,sq3=0;
    for (int n = n0; n < n1; ++n) {
        int ga = n*DIM + d;
        float e0 = E[ga];
        float e1 = E[1*NENT*DIM + ga];
        float e2 = E[2*NENT*DIM + ga];
        float e3 = E[3*NENT*DIM + ga];
        float inv = rsqrtf(e0*e0+e1*e1+e2*e2+e3*e3);
        e0*=inv; e1*=inv; e2*=inv; e3*=inv;
        Eh[ga]               = (_Float16)e0;
        Eh[1*NENT*DIM + ga]  = (_Float16)e1;
        Eh[2*NENT*DIM + ga]  = (_Float16)e2;
        Eh[3*NENT*DIM + ga]  = (_Float16)e3;
        sm0+=e0; sq0+=e0*e0;
        sm1+=e1; sq1+=e1*e1;
        sm2+=e2; sq2+=e2*e2;
        sm3+=e3; sq3+=e3*e3;
    }
    atomicAdd(&acc[0*DIM+d], sm0); atomicAdd(&acc[1024 + 0*DIM+d], sq0);
    atomicAdd(&acc[1*DIM+d], sm1); atomicAdd(&acc[1024 + 1*DIM+d], sq1);
    atomicAdd(&acc[2*DIM+d], sm2); atomicAdd(&acc[1024 + 2*DIM+d], sq2);
    atomicAdd(&acc[3*DIM+d], sm3); atomicAdd(&acc[1024 + 3*DIM+d], sq3);
}

// ---------------- Phase 2: BN stats over gathered batch h ----------------
__global__ void stats_batch_kernel(const float* __restrict__ E, const int* __restrict__ h_idx,
                                   float* __restrict__ accH) {
    int d = threadIdx.x;
    int b0 = blockIdx.x * 32;
    float sm0=0,sm1=0,sm2=0,sm3=0, sq0=0,sq1=0,sq2=0,sq3=0;
    for (int j = 0; j < 32; ++j) {
        int n = h_idx[b0 + j];
        int ga = n*DIM + d;
        float e0 = E[ga];
        float e1 = E[1*NENT*DIM + ga];
        float e2 = E[2*NENT*DIM + ga];
        float e3 = E[3*NENT*DIM + ga];
        float inv = rsqrtf(e0*e0+e1*e1+e2*e2+e3*e3);
        e0*=inv; e1*=inv; e2*=inv; e3*=inv;
        sm0+=e0; sq0+=e0*e0;
        sm1+=e1; sq1+=e1*e1;
        sm2+=e2; sq2+=e2*e2;
        sm3+=e3; sq3+=e3*e3;
    }
    atomicAdd(&accH[0*DIM+d], sm0); atomicAdd(&accH[1024 + 0*DIM+d], sq0);
    atomicAdd(&accH[1*DIM+d], sm1); atomicAdd(&accH[1024 + 1*DIM+d], sq1);
    atomicAdd(&accH[2*DIM+d], sm2); atomicAdd(&accH[1024 + 2*DIM+d], sq2);
    atomicAdd(&accH[3*DIM+d], sm3); atomicAdd(&accH[1024 + 3*DIM+d], sq3);
}

// ---------------- Phase 3: finalize stats ----------------
__global__ void finalize_stats_kernel(const float* __restrict__ acc, float* __restrict__ stats) {
    int i = blockIdx.x * blockDim.x + threadIdx.x;  // 0..1023 -> (c,d)
    float mE = acc[i] * (1.0f / NENT);
    float vE = acc[1024 + i] * (1.0f / NENT) - mE * mE;
    float mH = acc[2048 + i] * (1.0f / BATCH);
    float vH = acc[3072 + i] * (1.0f / BATCH) - mH * mH;
    stats[i]        = mE;
    stats[1024 + i] = rsqrtf(vE + EPSV);
    stats[2048 + i] = mH;
    stats[3072 + i] = rsqrtf(vH + EPSV);
}

// ---------------- Phase 4: build t' (BN-folded, f16) and K[c][b] ----------------
__global__ void build_t_kernel(const float* __restrict__ E, const float* __restrict__ R,
                               const float* __restrict__ psi_emb,
                               const float* __restrict__ gamma, const float* __restrict__ beta,
                               const int* __restrict__ h_idx, const int* __restrict__ r_idx,
                               const float* __restrict__ stats,
                               _Float16* __restrict__ th, float* __restrict__ Kc) {
    __shared__ float red[4];
    int b = blockIdx.x, d = threadIdx.x;
    int wave = d >> 6, lane = d & 63;
    int hn = h_idx[b], rn = r_idx[b];

    float hv[4];
    hv[0] = E[hn*DIM + d];
    hv[1] = E[1*NENT*DIM + hn*DIM + d];
    hv[2] = E[2*NENT*DIM + hn*DIM + d];
    hv[3] = E[3*NENT*DIM + hn*DIM + d];
    float invh = rsqrtf(hv[0]*hv[0]+hv[1]*hv[1]+hv[2]*hv[2]+hv[3]*hv[3]);
    float hq[4];
#pragma unroll
    for (int c = 0; c < 4; ++c) {
        float v = hv[c] * invh;
        float mH = stats[2048 + c*DIM + d], isH = stats[3072 + c*DIM + d];
        hq[c] = (v - mH) * isH * gamma[c*DIM + d] + beta[c*DIM + d];
    }

    float r0 = R[rn*DIM + d];
    float r1 = R[1*NREL*DIM + rn*DIM + d];
    float r2 = R[2*NREL*DIM + rn*DIM + d];
    float r3 = R[3*NREL*DIM + rn*DIM + d];
    float invr = rsqrtf(r0*r0+r1*r1+r2*r2+r3*r3);
    r0*=invr; r1*=invr; r2*=invr; r3*=invr;

    float p = psi_emb[rn*DIM + d];
    float cz = cosf(p), sz = sinf(p);

    float m1r = hq[0]*r0 - hq[1]*r1;
    float m1i = hq[0]*r1 + hq[1]*r0;
    float X   = hq[2]*r2 + hq[3]*r3;
    float Y   = hq[3]*r2 - hq[2]*r3;
    float m2r = cz*X - sz*Y;
    float m2i = cz*Y + sz*X;
    float m3r = hq[0]*r2 - hq[1]*r3;
    float m3i = hq[0]*r3 + hq[1]*r2;
    float U   = hq[2]*r0 + hq[3]*r1;
    float V   = hq[3]*r0 - hq[2]*r1;
    float m4r = cz*U - sz*V;
    float m4i = cz*V + sz*U;

    float t[4] = { m1r - m2r, m1i - m2i, m3r + m4r, m3i + m4i };

#pragma unroll
    for (int c = 0; c < 4; ++c) {
        float g   = gamma[c*DIM + d];
        float mE  = stats[c*DIM + d];
        float isE = stats[1024 + c*DIM + d];
        th[((size_t)c*BATCH + b)*DIM + d] = (_Float16)(t[c] * g * isE);
        float kp = t[c] * (beta[c*DIM + d] - g * mE * isE);
#pragma unroll
        for (int off = 32; off > 0; off >>= 1) kp += __shfl_down(kp, off, 64);
        if (lane == 0) red[wave] = kp;
        __syncthreads();
        if (d == 0) Kc[c*BATCH + b] = red[0] + red[1] + red[2] + red[3];
        __syncthreads();
    }
}

// ---------------- Phase 5: f16 MFMA GEMM + bias + sigmoid ----------------
// Block 128b x 128n, 4 waves (wave tile 64x64), K-chunk 32 (2 MFMA K-steps).
// LDS in fragment order: 16 frags of 1024B (A: 0..7, B: 8..15); ds_read at lane*16.
__launch_bounds__(256)
__global__ void score_gemm_kernel(const _Float16* __restrict__ th,  // [4][512][256]
                                  const _Float16* __restrict__ Eh,  // [4][50000][256]
                                  const float* __restrict__ Kc,     // [4][512]
                                  const float* __restrict__ biases, // [4][50000]
                                  float* __restrict__ out) {        // [4][512][50000]
    __shared__ __align__(1024) char smem[16384];
    int tid = threadIdx.x;
    int w = tid >> 6, l = tid & 63;
    int lr = l & 31, lh = l >> 5;
    int wm = w & 1, wn = w >> 1;            // wave m-half / n-half
    int c  = blockIdx.z;
    int b0 = blockIdx.y * 128;
    int n0 = blockIdx.x * 128;

    const _Float16* Ah = th + (size_t)c * BATCH * DIM;
    const _Float16* Bh = Eh + (size_t)c * NENT * DIM;

    f32x16 acc00 = zero16(), acc01 = zero16(), acc10 = zero16(), acc11 = zero16();

    for (int k0 = 0; k0 < DIM; k0 += 32) {
        __syncthreads();
        // stage 16 fragments; wave w issues frags [4w, 4w+4)
#pragma unroll
        for (int i = 0; i < 4; ++i) {
            int f = w * 4 + i;
            const _Float16* gp;
            if (f < 8) {                          // A frag: mf=f>>1, ks=f&1
                int mf = f >> 1, ks = f & 1;
                gp = Ah + (size_t)(b0 + mf*32 + lr) * DIM + k0 + ks*16 + lh*8;
            } else {                              // B frag
                int g = f - 8, nf = g >> 1, ks = g & 1;
                int n = n0 + nf*32 + lr; if (n > NENT-1) n = NENT-1;
                gp = Bh + (size_t)n * DIM + k0 + ks*16 + lh*8;
            }
            __builtin_amdgcn_global_load_lds(
                (const __attribute__((address_space(1))) void*)gp,
                (__attribute__((address_space(3))) void*)(smem + f * 1024),
                16, 0, 0);
        }
        __builtin_amdgcn_s_waitcnt(0x0f70);   // vmcnt(0)
        __syncthreads();

#pragma unroll
        for (int ks = 0; ks < 2; ++ks) {
            f16x8 a0 = *(const f16x8*)(smem + ((wm*2+0)*2 + ks)*1024 + l*16);
            f16x8 a1 = *(const f16x8*)(smem + ((wm*2+1)*2 + ks)*1024 + l*16);
            f16x8 bb0 = *(const f16x8*)(smem + 8192 + ((wn*2+0)*2 + ks)*1024 + l*16);
            f16x8 bb1 = *(const f16x8*)(smem + 8192 + ((wn*2+1)*2 + ks)*1024 + l*16);
            acc00 = __builtin_amdgcn_mfma_f32_32x32x16_f16(a0, bb0, acc00, 0, 0, 0);
            acc01 = __builtin_amdgcn_mfma_f32_32x32x16_f16(a0, bb1, acc01, 0, 0, 0);
            acc10 = __builtin_amdgcn_mfma_f32_32x32x16_f16(a1, bb0, acc10, 0, 0, 0);
            acc11 = __builtin_amdgcn_mfma_f32_32x32x16_f16(a1, bb1, acc11, 0, 0, 0);
        }
    }

    // epilogue: D[m][n]: n = lane&31, m = (reg&3)+8*(reg>>2)+4*(lane>>5)
    const float* Kcc = Kc + c * BATCH;
    const float* bc  = biases + (size_t)c * NENT;
    float* oc = out + (size_t)c * BATCH * NENT;
#pragma unroll
    for (int mi = 0; mi < 2; ++mi) {
#pragma unroll
        for (int ni = 0; ni < 2; ++ni) {
            const f32x16& a = (mi==0) ? (ni==0 ? acc00 : acc01) : (ni==0 ? acc10 : acc11);
            int n = n0 + wn*64 + ni*32 + lr;
            bool ok = (n < NENT);
            float bv = ok ? bc[n] : 0.f;
#pragma unroll
            for (int reg = 0; reg < 16; ++reg) {
                int m = b0 + wm*64 + mi*32 + (reg & 3) + 8*(reg >> 2) + 4*lh;
                float x = a[reg] + Kcc[m] + bv;
                if (ok) oc[(size_t)m * NENT + n] = 1.f / (1.f + __expf(-x));
            }
        }
    }
}

extern "C" void kernel_launch(void* const* d_in, const int* in_sizes, int n_in,
                              void* d_out, int out_size, void* d_ws, size_t ws_size,
                              hipStream_t stream) {
    const float* E      = (const float*)d_in[0];
    const float* R      = (const float*)d_in[1];
    const float* psi    = (const float*)d_in[2];
    const float* gamma  = (const float*)d_in[3];
    const float* beta   = (const float*)d_in[4];
    const float* biases = (const float*)d_in[5];
    const int* h_idx    = (const int*)d_in[6];
    const int* r_idx    = (const int*)d_in[7];
    float* out = (float*)d_out;
    float* ws  = (float*)d_ws;

    _Float16* th = (_Float16*)(ws + WS_F16);
    _Float16* Eh = th + (size_t)4 * BATCH * DIM;

    hipMemsetAsync(ws + WS_ACC, 0, 4096 * sizeof(float), stream);

    convert_stats_kernel<<<512, 256, 0, stream>>>(E, Eh, ws + WS_ACC);
    stats_batch_kernel<<<16, 256, 0, stream>>>(E, h_idx, ws + WS_ACC + 2048);
    finalize_stats_kernel<<<4, 256, 0, stream>>>(ws + WS_ACC, ws + WS_STATS);
    build_t_kernel<<<BATCH, 256, 0, stream>>>(E, R, psi, gamma, beta, h_idx, r_idx,
                                              ws + WS_STATS, th, ws + WS_KC);
    dim3 grid((NENT + 127) / 128, BATCH / 128, 4);
    score_gemm_kernel<<<grid, 256, 0, stream>>>(th, Eh, ws + WS_KC, biases, out);
}